// Round 9
// baseline (57.913 us; speedup 1.0000x reference)
//
#include <hip/hip_runtime.h>

// Dims
#define SS 96     // spatial
#define CC 32     // latent
#define TT 16     // time
#define BP 16     // B*P
#define MM 3072   // CC*SS; m = c*96 + e == x's natural [c][e] flat layout

// ---------------------------------------------------------------------------
// K1: prep (grid 769):
//   [0,192):   transpose Q,K slab: [e*32+c] -> [c*96+e]  (Qt, Kt)
//   [192,768): wa[X*1536 + v*16 + t] = w[v] * Aoo[X,v,t]
//              (Aoo axis0 = K-side X, axis1 = Q-side v — verified orientation)
//   768:       zero G (1536) and y (512)
__global__ __launch_bounds__(256) void k_prep(const float* __restrict__ Q,
                                              const float* __restrict__ K,
                                              const float* __restrict__ Aoo,
                                              const float* __restrict__ w,
                                              float* __restrict__ Qt,
                                              float* __restrict__ Kt,
                                              float* __restrict__ wa,
                                              float* __restrict__ G,
                                              float* __restrict__ y) {
    __shared__ float sbuf[SS * 33];
    const int bid = blockIdx.x, tid = threadIdx.x;
    if (bid < 192) {
        const float* src = (bid < SS) ? (Q + (size_t)bid * MM)
                                      : (K + (size_t)(bid - SS) * MM);
        float* dst = (bid < SS) ? (Qt + (size_t)bid * MM)
                                : (Kt + (size_t)(bid - SS) * MM);
        for (int i = tid; i < MM; i += 256) {
            int e = i >> 5, c = i & 31;
            sbuf[e * 33 + c] = src[i];
        }
        __syncthreads();
        for (int j = tid; j < MM; j += 256) {
            int c = j / SS, e = j - c * SS;
            dst[j] = sbuf[e * 33 + c];
        }
    } else if (bid < 768) {
        int idx = (bid - 192) * 256 + tid;
        wa[idx] = w[(idx >> 4) % SS] * Aoo[idx];
    } else {
        for (int i = tid; i < SS * BP; i += 256) G[i] = 0.f;
        for (int i = tid; i < BP * CC; i += 256) y[i] = 0.f;
    }
}

// ---------------------------------------------------------------------------
// K2: G[X,b] += sum_{t,m} [sum_v wa[X,v,t] Qt[v,m]] * Kt[X,m] * x[b,t,m]
// 1152 blocks; each block = 4 waves sharing ONE 64-wide m-range, one X per
// wave (R8 lesson: intra-block address sharing turns L2 loads into L1 hits;
// Qt footprint 24KB fits L1). No LDS/syncthreads: wave-level butterfly
// reduce + 16 atomics from lane 0. mc-major XCD chunking keeps each XCD's
// x-slice resident in its own L2.
__global__ __launch_bounds__(256) void k_main(const float* __restrict__ Qt,
                                              const float* __restrict__ Kt,
                                              const float* __restrict__ x,
                                              const float* __restrict__ wa,
                                              float* __restrict__ G) {
    const int tid = threadIdx.x;
    const int flat = blockIdx.x;                    // 0..1151
    const int wid = (flat & 7) * 144 + (flat >> 3); // XCD chunk (1152 = 8*144)
    const int mc = wid / 24;                        // 0..47, mc-major order
    const int xg = wid - mc * 24;                   // 0..23
    const int wv = __builtin_amdgcn_readfirstlane(tid >> 6);  // wave id 0..3
    const int lane = tid & 63;
    const int X = xg * 4 + wv;                      // one X per wave
    const int m = mc * 64 + lane;                   // 64 m per block, shared

    const float* wap = wa + (size_t)X * (SS * TT);  // wave-uniform -> s_loads
    const float* Qp = Qt + m;

    float pk[TT];
#pragma unroll
    for (int t = 0; t < TT; ++t) pk[t] = 0.f;

    for (int v0 = 0; v0 < SS; v0 += 4) {            // 4 loads in flight
        float q0 = Qp[(size_t)(v0 + 0) * MM];
        float q1 = Qp[(size_t)(v0 + 1) * MM];
        float q2 = Qp[(size_t)(v0 + 2) * MM];
        float q3 = Qp[(size_t)(v0 + 3) * MM];
        const float* w0 = wap + v0 * TT;            // uniform -> scalar loads
#pragma unroll
        for (int t = 0; t < TT; ++t) {
            float a = fmaf(w0[t], q0, pk[t]);
            float b = fmaf(w0[TT + t], q1, a);
            float c = fmaf(w0[2 * TT + t], q2, b);
            pk[t] = fmaf(w0[3 * TT + t], q3, c);
        }
    }
    const float kv = Kt[(size_t)X * MM + m];
#pragma unroll
    for (int t = 0; t < TT; ++t) pk[t] *= kv;

    float g[BP];
#pragma unroll
    for (int b = 0; b < BP; ++b) g[b] = 0.f;

    for (int b = 0; b < BP; b += 2) {               // 32 loads in flight
        const float* xp0 = x + (size_t)(b + 0) * (TT * MM) + m;
        const float* xp1 = x + (size_t)(b + 1) * (TT * MM) + m;
        float xv0[TT], xv1[TT];
#pragma unroll
        for (int t = 0; t < TT; ++t) xv0[t] = xp0[(size_t)t * MM];
#pragma unroll
        for (int t = 0; t < TT; ++t) xv1[t] = xp1[(size_t)t * MM];
#pragma unroll
        for (int t = 0; t < TT; ++t) {
            g[b] = fmaf(pk[t], xv0[t], g[b]);
            g[b + 1] = fmaf(pk[t], xv1[t], g[b + 1]);
        }
    }

    // butterfly reduce each g[b] across the 64 lanes (all lanes get the sum),
    // then lane 0 issues the 16 atomics (static indices — no scratch).
#pragma unroll
    for (int b = 0; b < BP; ++b) {
        float vv = g[b];
        vv += __shfl_xor(vv, 1, 64);
        vv += __shfl_xor(vv, 2, 64);
        vv += __shfl_xor(vv, 4, 64);
        vv += __shfl_xor(vv, 8, 64);
        vv += __shfl_xor(vv, 16, 64);
        vv += __shfl_xor(vv, 32, 64);
        g[b] = vv;
    }
    if (lane == 0) {
#pragma unroll
        for (int b = 0; b < BP; ++b)
            atomicAdd(&G[X * BP + b], g[b]);
    }
}

// ---------------------------------------------------------------------------
// K3: y[bp,c] += sum_{X in chunk xc} G[X,bp] * sum_e V[X,e,c]*x[bp,T-1,c,e]
__global__ __launch_bounds__(256) void k_y(const float* __restrict__ x,
                                           const float* __restrict__ V,
                                           const float* __restrict__ G,
                                           float* __restrict__ y) {
    const int bp = blockIdx.x;
    const int xc = blockIdx.y;
    const int tid = threadIdx.x;
    __shared__ float xl[SS * 33];   // xl[e*33+c] = x[bp,T-1,c,e] (conflict-free)
    __shared__ float red2[8 * CC];

    const float* xs = x + (size_t)bp * (TT * MM) + (TT - 1) * MM; // [c][e]
    for (int i = tid; i < MM; i += 256) {
        int c = i / SS, e = i - (i / SS) * SS;
        xl[e * 33 + c] = xs[i];
    }
    __syncthreads();

    const int c = tid & 31, grp = tid >> 5;
    const int X = xc * 8 + grp;
    const float* Vp = V + (size_t)X * MM + c;   // coalesced across c lanes
    float acc = 0.f;
#pragma unroll 8
    for (int e = 0; e < SS; ++e)
        acc = fmaf(Vp[e * CC], xl[e * 33 + c], acc);
    acc *= G[X * BP + bp];

    red2[grp * CC + c] = acc;
    __syncthreads();
    if (tid < CC) {
        float vv = 0.f;
#pragma unroll
        for (int g8 = 0; g8 < 8; ++g8) vv += red2[g8 * CC + tid];
        atomicAdd(&y[bp * CC + tid], vv);
    }
}

// ---------------------------------------------------------------------------
extern "C" void kernel_launch(void* const* d_in, const int* in_sizes, int n_in,
                              void* d_out, int out_size, void* d_ws, size_t ws_size,
                              hipStream_t stream) {
    const float* x   = (const float*)d_in[0];
    const float* Q   = (const float*)d_in[1];
    const float* K   = (const float*)d_in[2];
    const float* V   = (const float*)d_in[3];
    const float* Aoo = (const float*)d_in[4];
    const float* w   = (const float*)d_in[5];

    float* ws = (float*)d_ws;
    float* Qt = ws;                        // 294912 floats
    float* Kt = ws + 294912;               // 294912 floats
    float* wa = ws + 2 * 294912;           // 147456 floats
    float* G  = ws + 2 * 294912 + 147456;  // 1536 floats
    float* y  = (float*)d_out;

    k_prep<<<dim3(769), 256, 0, stream>>>(Q, K, Aoo, w, Qt, Kt, wa, G, y);
    k_main<<<dim3(1152), 256, 0, stream>>>(Qt, Kt, x, wa, G);
    k_y<<<dim3(BP, 12), 256, 0, stream>>>(x, V, G, y);
}

// Round 10
// 45.271 us; speedup vs baseline: 1.2792x; 1.2792x over previous
//
#include <hip/hip_runtime.h>

// Dims
#define SS 96     // spatial
#define CC 32     // latent
#define TT 16     // time
#define BP 16     // B*P
#define MM 3072   // CC*SS; m = c*96 + e == x's natural [c][e] flat layout

// ---------------------------------------------------------------------------
// K1: prep (grid 769):
//   [0,192):   transpose Q,K slab: [e*32+c] -> [c*96+e]  (Qt, Kt)
//   [192,768): wa[X*1536 + v*16 + t] = w[v] * Aoo[X,v,t]
//   768:       zero G (1536) and y (512)
__global__ __launch_bounds__(256) void k_prep(const float* __restrict__ Q,
                                              const float* __restrict__ K,
                                              const float* __restrict__ Aoo,
                                              const float* __restrict__ w,
                                              float* __restrict__ Qt,
                                              float* __restrict__ Kt,
                                              float* __restrict__ wa,
                                              float* __restrict__ G,
                                              float* __restrict__ y) {
    __shared__ float sbuf[SS * 33];
    const int bid = blockIdx.x, tid = threadIdx.x;
    if (bid < 192) {
        const float* src = (bid < SS) ? (Q + (size_t)bid * MM)
                                      : (K + (size_t)(bid - SS) * MM);
        float* dst = (bid < SS) ? (Qt + (size_t)bid * MM)
                                : (Kt + (size_t)(bid - SS) * MM);
        for (int i = tid; i < MM; i += 256) {
            int e = i >> 5, c = i & 31;
            sbuf[e * 33 + c] = src[i];
        }
        __syncthreads();
        for (int j = tid; j < MM; j += 256) {
            int c = j / SS, e = j - c * SS;
            dst[j] = sbuf[e * 33 + c];
        }
    } else if (bid < 768) {
        int idx = (bid - 192) * 256 + tid;
        wa[idx] = w[(idx >> 4) % SS] * Aoo[idx];
    } else {
        for (int i = tid; i < SS * BP; i += 256) G[i] = 0.f;
        for (int i = tid; i < BP * CC; i += 256) y[i] = 0.f;
    }
}

// ---------------------------------------------------------------------------
// K2: G[X,b] += sum_{t,m} [sum_v wa[X,v,t] Qt[v,m]] * Kt[X,m] * x[b,t,m]
// R8 structure (best measured): X per block, 256-wide m, 1152 blocks, LDS
// reduce -> 1 atomic per (X,b) per block, XCD-chunked swizzle.
// New: explicit software pipelining (register rotation) so next iteration's
// loads are in flight under the current iteration's FMAs — never drain.
__global__ __launch_bounds__(256) void k_main(const float* __restrict__ Qt,
                                              const float* __restrict__ Kt,
                                              const float* __restrict__ x,
                                              const float* __restrict__ wa,
                                              float* __restrict__ G) {
    const int tid = threadIdx.x;
    const int flat = blockIdx.x + gridDim.x * blockIdx.y;
    const int wid = (flat & 7) * 144 + (flat >> 3); // XCD chunk (1152 = 8*144)
    const int X = wid % SS;                         // mc-major work order
    const int mc = wid / SS;
    const int m = mc * 256 + tid;

    const float* wap = wa + (size_t)X * (SS * TT);  // wave-uniform -> s_loads
    const float* Qp = Qt + m;

    float pk[TT];
#pragma unroll
    for (int t = 0; t < TT; ++t) pk[t] = 0.f;

    // ---- v-loop, pipelined: prefetch v0+4..7 while FMA-ing v0..3.
    // Last-iter prefetch overruns Qt into Kt (same ws buffer) — harmless junk.
    float q0 = Qp[0], q1 = Qp[MM], q2 = Qp[2 * MM], q3 = Qp[3 * MM];
    for (int v0 = 0; v0 < SS; v0 += 4) {
        float n0 = Qp[(size_t)(v0 + 4) * MM];
        float n1 = Qp[(size_t)(v0 + 5) * MM];
        float n2 = Qp[(size_t)(v0 + 6) * MM];
        float n3 = Qp[(size_t)(v0 + 7) * MM];
        const float* w0 = wap + v0 * TT;            // uniform -> scalar loads
#pragma unroll
        for (int t = 0; t < TT; ++t) {
            float a = fmaf(w0[t], q0, pk[t]);
            float b = fmaf(w0[TT + t], q1, a);
            float c = fmaf(w0[2 * TT + t], q2, b);
            pk[t] = fmaf(w0[3 * TT + t], q3, c);
        }
        q0 = n0; q1 = n1; q2 = n2; q3 = n3;
    }
    const float kv = Kt[(size_t)X * MM + m];
#pragma unroll
    for (int t = 0; t < TT; ++t) pk[t] *= kv;

    // ---- b-loop, pipelined two pairs deep (indices clamped with &15: the
    // final prefetch re-reads pair (0,1) instead of running past x).
    float g[BP];
#pragma unroll
    for (int b = 0; b < BP; ++b) g[b] = 0.f;

    float xa[TT], xb[TT], ya[TT], yb[TT];
    {
        const float* p0 = x + (size_t)0 * (TT * MM) + m;
        const float* p1 = x + (size_t)1 * (TT * MM) + m;
#pragma unroll
        for (int t = 0; t < TT; ++t) { xa[t] = p0[(size_t)t * MM]; xb[t] = p1[(size_t)t * MM]; }
    }
#pragma unroll
    for (int bb = 0; bb < BP; bb += 4) {
        {   // prefetch pair (bb+2, bb+3) into y*
            const float* p0 = x + (size_t)((bb + 2) & 15) * (TT * MM) + m;
            const float* p1 = x + (size_t)((bb + 3) & 15) * (TT * MM) + m;
#pragma unroll
            for (int t = 0; t < TT; ++t) { ya[t] = p0[(size_t)t * MM]; yb[t] = p1[(size_t)t * MM]; }
        }
#pragma unroll
        for (int t = 0; t < TT; ++t) {
            g[bb]     = fmaf(pk[t], xa[t], g[bb]);
            g[bb + 1] = fmaf(pk[t], xb[t], g[bb + 1]);
        }
        {   // prefetch pair (bb+4, bb+5) into x*
            const float* p0 = x + (size_t)((bb + 4) & 15) * (TT * MM) + m;
            const float* p1 = x + (size_t)((bb + 5) & 15) * (TT * MM) + m;
#pragma unroll
            for (int t = 0; t < TT; ++t) { xa[t] = p0[(size_t)t * MM]; xb[t] = p1[(size_t)t * MM]; }
        }
#pragma unroll
        for (int t = 0; t < TT; ++t) {
            g[bb + 2] = fmaf(pk[t], ya[t], g[bb + 2]);
            g[bb + 3] = fmaf(pk[t], yb[t], g[bb + 3]);
        }
    }

    // reduce the 16 per-thread partials across the block, one atomic per (X,b)
#pragma unroll
    for (int b = 0; b < BP; ++b) {
        float vv = g[b];
        vv += __shfl_down(vv, 32, 64);
        vv += __shfl_down(vv, 16, 64);
        vv += __shfl_down(vv, 8, 64);
        vv += __shfl_down(vv, 4, 64);
        vv += __shfl_down(vv, 2, 64);
        vv += __shfl_down(vv, 1, 64);
        g[b] = vv;
    }
    __shared__ float wred[4 * BP];
    const int lane = tid & 63, wwid = tid >> 6;
    if (lane == 0) {
#pragma unroll
        for (int b = 0; b < BP; ++b) wred[wwid * BP + b] = g[b];
    }
    __syncthreads();
    if (tid < BP) {
        float vv = wred[tid] + wred[BP + tid] + wred[2 * BP + tid] +
                   wred[3 * BP + tid];
        atomicAdd(&G[X * BP + tid], vv);
    }
}

// ---------------------------------------------------------------------------
// K3: y[bp,c] += sum_{X in chunk xc} G[X,bp] * sum_e V[X,e,c]*x[bp,T-1,c,e]
__global__ __launch_bounds__(256) void k_y(const float* __restrict__ x,
                                           const float* __restrict__ V,
                                           const float* __restrict__ G,
                                           float* __restrict__ y) {
    const int bp = blockIdx.x;
    const int xc = blockIdx.y;
    const int tid = threadIdx.x;
    __shared__ float xl[SS * 33];   // xl[e*33+c] = x[bp,T-1,c,e] (conflict-free)
    __shared__ float red2[8 * CC];

    const float* xs = x + (size_t)bp * (TT * MM) + (TT - 1) * MM; // [c][e]
    for (int i = tid; i < MM; i += 256) {
        int c = i / SS, e = i - (i / SS) * SS;
        xl[e * 33 + c] = xs[i];
    }
    __syncthreads();

    const int c = tid & 31, grp = tid >> 5;
    const int X = xc * 8 + grp;
    const float* Vp = V + (size_t)X * MM + c;   // coalesced across c lanes
    float acc = 0.f;
#pragma unroll 8
    for (int e = 0; e < SS; ++e)
        acc = fmaf(Vp[e * CC], xl[e * 33 + c], acc);
    acc *= G[X * BP + bp];

    red2[grp * CC + c] = acc;
    __syncthreads();
    if (tid < CC) {
        float vv = 0.f;
#pragma unroll
        for (int g8 = 0; g8 < 8; ++g8) vv += red2[g8 * CC + tid];
        atomicAdd(&y[bp * CC + tid], vv);
    }
}

// ---------------------------------------------------------------------------
extern "C" void kernel_launch(void* const* d_in, const int* in_sizes, int n_in,
                              void* d_out, int out_size, void* d_ws, size_t ws_size,
                              hipStream_t stream) {
    const float* x   = (const float*)d_in[0];
    const float* Q   = (const float*)d_in[1];
    const float* K   = (const float*)d_in[2];
    const float* V   = (const float*)d_in[3];
    const float* Aoo = (const float*)d_in[4];
    const float* w   = (const float*)d_in[5];

    float* ws = (float*)d_ws;
    float* Qt = ws;                        // 294912 floats
    float* Kt = ws + 294912;               // 294912 floats (v-loop prefetch may read its head — benign)
    float* wa = ws + 2 * 294912;           // 147456 floats
    float* G  = ws + 2 * 294912 + 147456;  // 1536 floats
    float* y  = (float*)d_out;

    k_prep<<<dim3(769), 256, 0, stream>>>(Q, K, Aoo, w, Qt, Kt, wa, G, y);
    k_main<<<dim3(1152), 256, 0, stream>>>(Qt, Kt, x, wa, G);
    k_y<<<dim3(BP, 12), 256, 0, stream>>>(x, V, G, y);
}

// Round 11
// 41.736 us; speedup vs baseline: 1.3876x; 1.0847x over previous
//
#include <hip/hip_runtime.h>

// Dims
#define SS 96     // spatial
#define CC 32     // latent
#define TT 16     // time
#define BP 16     // B*P
#define MM 3072   // CC*SS; m = c*96 + e == x's natural [c][e] flat layout
#define KTOT 49152  // TT*MM: flattened (t,m) contraction axis for GEMM2

typedef float f32x4 __attribute__((ext_vector_type(4)));
typedef short short8 __attribute__((ext_vector_type(8)));

// fp32 -> bf16 round-to-nearest-even
__device__ __forceinline__ unsigned short f2b(float f) {
    union { float f; unsigned u; } a; a.f = f;
    unsigned r = a.u + 0x7FFFu + ((a.u >> 16) & 1u);
    return (unsigned short)(r >> 16);
}

// ---------------------------------------------------------------------------
// K1: prep (grid 673):
//   [0,96):    Kt[X][c*96+e] = K[X][e*32+c]                  (fp32)
//   [96,192):  Qb[(c*96+e)][v] = bf16(Q[v][e*32+c])          (A of GEMM1)
//   [192,288): wab[X][t*96+v] = bf16(w[v]*Aoo[X][v*16+t])    (B of GEMM1)
//              (Aoo axis0 = K-side X, axis1 = Q-side v — verified orientation)
//   [288,672): xb = bf16(x)  (natural layout = [b][t*3072+m]) (B of GEMM2)
//   672:       zero y (512)
__global__ __launch_bounds__(256) void k_prep(
    const float* __restrict__ x, const float* __restrict__ Q,
    const float* __restrict__ K, const float* __restrict__ Aoo,
    const float* __restrict__ w, float* __restrict__ Kt,
    unsigned short* __restrict__ Qb, unsigned short* __restrict__ wab,
    unsigned short* __restrict__ xb, float* __restrict__ y)
{
    __shared__ float sb[SS * 33];
    const int bid = blockIdx.x, tid = threadIdx.x;
    if (bid < 96) {
        const int X = bid;
        const float* src = K + (size_t)X * MM;
        float* dst = Kt + (size_t)X * MM;
        for (int i = tid; i < MM; i += 256) {
            int e = i >> 5, c = i & 31;
            sb[e * 33 + c] = src[i];
        }
        __syncthreads();
        for (int j = tid; j < MM; j += 256) {
            int c = j / SS, e = j - c * SS;
            dst[j] = sb[e * 33 + c];
        }
    } else if (bid < 192) {
        const int e = bid - 96;           // one e-slab: all (v, c)
        for (int i = tid; i < MM; i += 256) {     // i = v*32 + c
            int v = i >> 5, c = i & 31;
            sb[v * 33 + c] = Q[(size_t)v * MM + e * 32 + c];
        }
        __syncthreads();
        for (int j = tid; j < MM; j += 256) {     // j = c*96 + v
            int c = j / SS, v = j - c * SS;
            Qb[(size_t)(c * SS + e) * SS + v] = f2b(sb[v * 33 + c]);
        }
    } else if (bid < 288) {
        const int X = bid - 192;
        for (int i = tid; i < SS * TT; i += 256) {  // i = v*16 + t
            int v = i >> 4, t = i & 15;
            sb[v * 17 + t] = Aoo[(size_t)X * (SS * TT) + i];
        }
        __syncthreads();
        for (int j = tid; j < SS * TT; j += 256) {  // j = t*96 + v
            int t = j / SS, v = j - t * SS;
            wab[(size_t)X * (SS * TT) + j] = f2b(w[v] * sb[v * 17 + t]);
        }
    } else if (bid < 672) {
        const size_t base = ((size_t)(bid - 288) * 256 + tid) * 8;
        float4 a = *(const float4*)(x + base);
        float4 b = *(const float4*)(x + base + 4);
        ushort4 o0, o1;
        o0.x = f2b(a.x); o0.y = f2b(a.y); o0.z = f2b(a.z); o0.w = f2b(a.w);
        o1.x = f2b(b.x); o1.y = f2b(b.y); o1.z = f2b(b.z); o1.w = f2b(b.w);
        *(ushort4*)(xb + base) = o0;
        *(ushort4*)(xb + base + 4) = o1;
    } else {
        y[tid] = 0.f; y[tid + 256] = 0.f;
    }
}

// ---------------------------------------------------------------------------
// K2 (MFMA GEMM1): per (X, mc): C[m(256) x t(16)] = Qb[m,v] x wab[t,v]^T
// then W2[X][t*3072+m] = bf16( C * Kt[X][m] ).
// Wave = 64 m (4 tiles of 16). A row (lane&15)=m, B col (lane&15)=t,
// k = 32*ks + 8*(lane>>4) + j; C: col(lane&15)=t, row((lane>>4)*4+r)=m.
__global__ __launch_bounds__(256) void k_gemm1(
    const unsigned short* __restrict__ Qb, const unsigned short* __restrict__ wab,
    const float* __restrict__ Kt, unsigned short* __restrict__ W2)
{
    const int tid = threadIdx.x;
    const int X = blockIdx.x;      // 96
    const int mc = blockIdx.y;     // 12
    const int lane = tid & 63, wv = tid >> 6;
    const int mbase = mc * 256 + wv * 64;
    const int l15 = lane & 15, lg = lane >> 4;

    const unsigned short* bw = wab + (size_t)X * (SS * TT) + l15 * SS + lg * 8;
    const short8 bf0 = *(const short8*)(bw);
    const short8 bf1 = *(const short8*)(bw + 32);
    const short8 bf2 = *(const short8*)(bw + 64);

    const f32x4 zero = {0.f, 0.f, 0.f, 0.f};
#pragma unroll
    for (int nt = 0; nt < 4; ++nt) {
        const int mrow = mbase + nt * 16 + l15;
        const unsigned short* ap = Qb + (size_t)mrow * SS + lg * 8;
        const short8 a0 = *(const short8*)(ap);
        const short8 a1 = *(const short8*)(ap + 32);
        const short8 a2 = *(const short8*)(ap + 64);
        f32x4 acc = zero;
        acc = __builtin_amdgcn_mfma_f32_16x16x32_bf16(a0, bf0, acc, 0, 0, 0);
        acc = __builtin_amdgcn_mfma_f32_16x16x32_bf16(a1, bf1, acc, 0, 0, 0);
        acc = __builtin_amdgcn_mfma_f32_16x16x32_bf16(a2, bf2, acc, 0, 0, 0);
        const int mout = mbase + nt * 16 + lg * 4;     // 4 consecutive m (r)
        const f32x4 kt4 = *(const f32x4*)(Kt + (size_t)X * MM + mout);
        ushort4 o;
        o.x = f2b(acc[0] * kt4[0]);
        o.y = f2b(acc[1] * kt4[1]);
        o.z = f2b(acc[2] * kt4[2]);
        o.w = f2b(acc[3] * kt4[3]);
        *(ushort4*)(W2 + (size_t)X * KTOT + (size_t)l15 * MM + mout) = o;
    }
}

// ---------------------------------------------------------------------------
// K3 (MFMA GEMM2, split-K): Gp[kb][X*16+b] = sum_{k-chunk} W2[X,k]*xb[b,k]
// 48 blocks x 4 waves; wave K-chunk 256 (8 k-steps); 6 X-tiles of 16.
// A row (lane&15)=X, B col (lane&15)=b; C: col=b, row=(lane>>4)*4+r = X_local.
__global__ __launch_bounds__(256) void k_gemm2(
    const unsigned short* __restrict__ W2, const unsigned short* __restrict__ xb,
    float* __restrict__ Gp)
{
    __shared__ float red[4 * 6 * 64 * 4];   // 24 KB
    const int tid = threadIdx.x;
    const int kb = blockIdx.x;              // 48
    const int lane = tid & 63, wv = tid >> 6;
    const int l15 = lane & 15, lg = lane >> 4;
    const int kw0 = kb * 1024 + wv * 256;

    const f32x4 zero = {0.f, 0.f, 0.f, 0.f};
    f32x4 acc[6];
#pragma unroll
    for (int xt = 0; xt < 6; ++xt) acc[xt] = zero;

    const unsigned short* xrow = xb + (size_t)l15 * KTOT + lg * 8;
#pragma unroll
    for (int ks = 0; ks < 8; ++ks) {
        const int k = kw0 + ks * 32;
        const short8 bf = *(const short8*)(xrow + k);
#pragma unroll
        for (int xt = 0; xt < 6; ++xt) {
            const unsigned short* ap =
                W2 + (size_t)(xt * 16 + l15) * KTOT + k + lg * 8;
            const short8 af = *(const short8*)(ap);
            acc[xt] = __builtin_amdgcn_mfma_f32_16x16x32_bf16(af, bf, acc[xt], 0, 0, 0);
        }
    }
#pragma unroll
    for (int xt = 0; xt < 6; ++xt)
#pragma unroll
        for (int r = 0; r < 4; ++r)
            red[((wv * 6 + xt) * 64 + lane) * 4 + r] = acc[xt][r];
    __syncthreads();
    for (int i = tid; i < 1536; i += 256) {         // i = X*16 + b
        const int Xv = i >> 4, b = i & 15;
        const int xt = Xv >> 4, Xl = Xv & 15;
        const int l = (Xl >> 2) * 16 + b, r = Xl & 3;
        float s = red[((0 * 6 + xt) * 64 + l) * 4 + r]
                + red[((1 * 6 + xt) * 64 + l) * 4 + r]
                + red[((2 * 6 + xt) * 64 + l) * 4 + r]
                + red[((3 * 6 + xt) * 64 + l) * 4 + r];
        Gp[(size_t)kb * 1536 + i] = s;
    }
}

// ---------------------------------------------------------------------------
// K4: y[bp,c] += sum_{X in xc} G[X,bp] * sum_e V[X,e,c]*x[bp,T-1,c,e]
// G gathered from the 48 split-K partials in-kernel (fp32, deterministic).
__global__ __launch_bounds__(256) void k_y(
    const float* __restrict__ x, const float* __restrict__ V,
    const float* __restrict__ Gp, float* __restrict__ y)
{
    const int bp = blockIdx.x, xc = blockIdx.y, tid = threadIdx.x;
    __shared__ float xl[SS * 33];
    __shared__ float red2[8 * CC];
    __shared__ float Gl[8];

    const float* xs = x + (size_t)bp * (TT * MM) + (TT - 1) * MM;
    for (int i = tid; i < MM; i += 256) {
        int c = i / SS, e = i - (i / SS) * SS;
        xl[e * 33 + c] = xs[i];
    }
    {
        const int xi = tid >> 5, j = tid & 31;
        const int gidx = (xc * 8 + xi) * BP + bp;
        float s = Gp[(size_t)j * 1536 + gidx];
        if (j < 16) s += Gp[(size_t)(j + 32) * 1536 + gidx];
        s += __shfl_down(s, 16, 32);
        s += __shfl_down(s, 8, 32);
        s += __shfl_down(s, 4, 32);
        s += __shfl_down(s, 2, 32);
        s += __shfl_down(s, 1, 32);
        if (j == 0) Gl[xi] = s;
    }
    __syncthreads();

    const int c = tid & 31, grp = tid >> 5;
    const float* Vp = V + (size_t)(xc * 8 + grp) * MM + c;
    float acc = 0.f;
#pragma unroll 8
    for (int e = 0; e < SS; ++e)
        acc = fmaf(Vp[e * CC], xl[e * 33 + c], acc);
    acc *= Gl[grp];

    red2[grp * CC + c] = acc;
    __syncthreads();
    if (tid < CC) {
        float vv = 0.f;
#pragma unroll
        for (int g8 = 0; g8 < 8; ++g8) vv += red2[g8 * CC + tid];
        atomicAdd(&y[bp * CC + tid], vv);
    }
}

// ---------------------------------------------------------------------------
extern "C" void kernel_launch(void* const* d_in, const int* in_sizes, int n_in,
                              void* d_out, int out_size, void* d_ws, size_t ws_size,
                              hipStream_t stream) {
    const float* x   = (const float*)d_in[0];
    const float* Q   = (const float*)d_in[1];
    const float* K   = (const float*)d_in[2];
    const float* V   = (const float*)d_in[3];
    const float* Aoo = (const float*)d_in[4];
    const float* w   = (const float*)d_in[5];

    char* wsb = (char*)d_ws;                    // 16B-aligned offsets
    float*          Kt  = (float*)(wsb);                  // 1,179,648 B
    float*          Gp  = (float*)(wsb + 1179648);        //   294,912 B
    unsigned short* Qb  = (unsigned short*)(wsb + 1474560); // 589,824 B
    unsigned short* wab = (unsigned short*)(wsb + 2064384); // 294,912 B
    unsigned short* xb  = (unsigned short*)(wsb + 2359296); // 1,572,864 B
    unsigned short* W2  = (unsigned short*)(wsb + 3932160); // 9,437,184 B
    float* y = (float*)d_out;                   // total ws: ~13.4 MB

    k_prep<<<dim3(673), 256, 0, stream>>>(x, Q, K, Aoo, w, Kt, Qb, wab, xb, y);
    k_gemm1<<<dim3(96, 12), 256, 0, stream>>>(Qb, wab, Kt, W2);
    k_gemm2<<<dim3(48), 256, 0, stream>>>(W2, xb, Gp);
    k_y<<<dim3(BP, 12), 256, 0, stream>>>(x, V, Gp, y);
}

// Round 12
// 37.498 us; speedup vs baseline: 1.5444x; 1.1130x over previous
//
#include <hip/hip_runtime.h>

// Dims
#define SS 96       // spatial
#define CC 32       // latent
#define TT 16       // time
#define BP 16       // B*P
#define MM 3072     // CC*SS; m = c*96 + e == x's natural [c][e] flat layout
#define KTOT 49152  // TT*MM: flattened (t,m) contraction axis for GEMM2
#define NKB 48      // split-K partial count in GEMM2

typedef float f32x4 __attribute__((ext_vector_type(4)));
typedef short short8 __attribute__((ext_vector_type(8)));

// fp32 -> bf16 round-to-nearest-even
__device__ __forceinline__ unsigned short f2b(float f) {
    union { float f; unsigned u; } a; a.f = f;
    unsigned r = a.u + 0x7FFFu + ((a.u >> 16) & 1u);
    return (unsigned short)(r >> 16);
}

// ---------------------------------------------------------------------------
// K1: prep (grid 288):
//   [0,96):    Kt[X][c*96+e] = K[X][e*32+c]                  (fp32)
//   [96,192):  Qb[(c*96+e)][v] = bf16(Q[v][e*32+c])          (A of GEMM1)
//   [192,288): wab[X][t*96+v] = bf16(w[v]*Aoo[X][v*16+t])    (B of GEMM1)
//              (Aoo axis0 = K-side X, axis1 = Q-side v — verified orientation)
__global__ __launch_bounds__(256) void k_prep(
    const float* __restrict__ Q, const float* __restrict__ K,
    const float* __restrict__ Aoo, const float* __restrict__ w,
    float* __restrict__ Kt, unsigned short* __restrict__ Qb,
    unsigned short* __restrict__ wab)
{
    __shared__ float sb[SS * 33];
    const int bid = blockIdx.x, tid = threadIdx.x;
    if (bid < 96) {
        const int X = bid;
        const float* src = K + (size_t)X * MM;
        float* dst = Kt + (size_t)X * MM;
        for (int i = tid; i < MM; i += 256) {
            int e = i >> 5, c = i & 31;
            sb[e * 33 + c] = src[i];
        }
        __syncthreads();
        for (int j = tid; j < MM; j += 256) {
            int c = j / SS, e = j - c * SS;
            dst[j] = sb[e * 33 + c];
        }
    } else if (bid < 192) {
        const int e = bid - 96;                    // one e-slab: all (v, c)
        for (int i = tid; i < MM; i += 256) {      // i = v*32 + c
            int v = i >> 5, c = i & 31;
            sb[v * 33 + c] = Q[(size_t)v * MM + e * 32 + c];
        }
        __syncthreads();
        for (int j = tid; j < MM; j += 256) {      // j = c*96 + v
            int c = j / SS, v = j - c * SS;
            Qb[(size_t)(c * SS + e) * SS + v] = f2b(sb[v * 33 + c]);
        }
    } else {
        const int X = bid - 192;
        for (int i = tid; i < SS * TT; i += 256) { // i = v*16 + t
            int v = i >> 4, t = i & 15;
            sb[v * 17 + t] = Aoo[(size_t)X * (SS * TT) + i];
        }
        __syncthreads();
        for (int j = tid; j < SS * TT; j += 256) { // j = t*96 + v
            int t = j / SS, v = j - t * SS;
            wab[(size_t)X * (SS * TT) + j] = f2b(w[v] * sb[v * 17 + t]);
        }
    }
}

// ---------------------------------------------------------------------------
// K2 (GEMM1 + xb convert, grid 1536):
//   bid<1152: per (X, mc): C[m(256) x t(16)] = Qb[m,v] x wab[t,v]^T, then
//             W2[X][t*3072+m] = bf16(C * Kt[X][m]).   (layout verified R11)
//   bid>=1152: xb = bf16(x) (natural flat layout) — only needed by GEMM2,
//              so it overlaps GEMM1 here instead of gating it in prep.
__global__ __launch_bounds__(256) void k_gemm1x(
    const unsigned short* __restrict__ Qb, const unsigned short* __restrict__ wab,
    const float* __restrict__ Kt, const float* __restrict__ x,
    unsigned short* __restrict__ W2, unsigned short* __restrict__ xb)
{
    const int tid = threadIdx.x, bid = blockIdx.x;
    if (bid >= 1152) {
        const size_t base = ((size_t)(bid - 1152) * 256 + tid) * 8;
        float4 a = *(const float4*)(x + base);
        float4 b = *(const float4*)(x + base + 4);
        ushort4 o0, o1;
        o0.x = f2b(a.x); o0.y = f2b(a.y); o0.z = f2b(a.z); o0.w = f2b(a.w);
        o1.x = f2b(b.x); o1.y = f2b(b.y); o1.z = f2b(b.z); o1.w = f2b(b.w);
        *(ushort4*)(xb + base) = o0;
        *(ushort4*)(xb + base + 4) = o1;
        return;
    }
    const int X = bid / 12;
    const int mc = bid - X * 12;
    const int lane = tid & 63, wv = tid >> 6;
    const int mbase = mc * 256 + wv * 64;
    const int l15 = lane & 15, lg = lane >> 4;

    const unsigned short* bw = wab + (size_t)X * (SS * TT) + l15 * SS + lg * 8;
    const short8 bf0 = *(const short8*)(bw);
    const short8 bf1 = *(const short8*)(bw + 32);
    const short8 bf2 = *(const short8*)(bw + 64);

    const f32x4 zero = {0.f, 0.f, 0.f, 0.f};
#pragma unroll
    for (int nt = 0; nt < 4; ++nt) {
        const int mrow = mbase + nt * 16 + l15;
        const unsigned short* ap = Qb + (size_t)mrow * SS + lg * 8;
        const short8 a0 = *(const short8*)(ap);
        const short8 a1 = *(const short8*)(ap + 32);
        const short8 a2 = *(const short8*)(ap + 64);
        f32x4 acc = zero;
        acc = __builtin_amdgcn_mfma_f32_16x16x32_bf16(a0, bf0, acc, 0, 0, 0);
        acc = __builtin_amdgcn_mfma_f32_16x16x32_bf16(a1, bf1, acc, 0, 0, 0);
        acc = __builtin_amdgcn_mfma_f32_16x16x32_bf16(a2, bf2, acc, 0, 0, 0);
        const int mout = mbase + nt * 16 + lg * 4;     // 4 consecutive m (r)
        const f32x4 kt4 = *(const f32x4*)(Kt + (size_t)X * MM + mout);
        ushort4 o;
        o.x = f2b(acc[0] * kt4[0]);
        o.y = f2b(acc[1] * kt4[1]);
        o.z = f2b(acc[2] * kt4[2]);
        o.w = f2b(acc[3] * kt4[3]);
        *(ushort4*)(W2 + (size_t)X * KTOT + (size_t)l15 * MM + mout) = o;
    }
}

// ---------------------------------------------------------------------------
// K3 (GEMM2 split-K + q, grid 480):
//   bid<288: (kb, Xt) block: Gp[(X*16+b)*48+kb] = sum_{k in kb-chunk}
//            W2[X,k]*xb[b,k].  kb-chunk 1024; 4 waves x 256k x 8 MFMAs.
//            Transposed Gp layout -> k_final reads contiguous 48-float runs.
//   bid>=288: q[bp][X][c] = sum_e V[X,e,c]*x[bp,T-1,c,e] (independent of G).
// No atomics anywhere; every output element written exactly once.
__global__ __launch_bounds__(256) void k_gemm2q(
    const unsigned short* __restrict__ W2, const unsigned short* __restrict__ xb,
    const float* __restrict__ x, const float* __restrict__ V,
    float* __restrict__ Gp, float* __restrict__ q)
{
    __shared__ float smem[SS * 33];            // gemm2 uses first 1024 floats
    const int tid = threadIdx.x, bid = blockIdx.x;
    if (bid < 288) {
        const int kb = bid / 6, Xt = bid - (bid / 6) * 6;
        const int lane = tid & 63, wv = tid >> 6;
        const int l15 = lane & 15, lg = lane >> 4;
        const int k0 = kb * 1024 + wv * 256;

        f32x4 acc = {0.f, 0.f, 0.f, 0.f};
        const unsigned short* xrow = xb + (size_t)l15 * KTOT + k0 + lg * 8;
        const unsigned short* arow =
            W2 + (size_t)(Xt * 16 + l15) * KTOT + k0 + lg * 8;
#pragma unroll
        for (int ks = 0; ks < 8; ++ks) {
            const short8 bf = *(const short8*)(xrow + ks * 32);
            const short8 af = *(const short8*)(arow + ks * 32);
            acc = __builtin_amdgcn_mfma_f32_16x16x32_bf16(af, bf, acc, 0, 0, 0);
        }
#pragma unroll
        for (int r = 0; r < 4; ++r)
            smem[(wv * 64 + lane) * 4 + r] = acc[r];
        __syncthreads();
        {   // i = Xl*16 + b; C layout: col(l&15)=b, row((l>>4)*4+r)=Xl
            const int Xl = tid >> 4, b = tid & 15;
            const int l = (Xl >> 2) * 16 + b, r = Xl & 3;
            float s = smem[(0 * 64 + l) * 4 + r] + smem[(1 * 64 + l) * 4 + r] +
                      smem[(2 * 64 + l) * 4 + r] + smem[(3 * 64 + l) * 4 + r];
            Gp[(size_t)((Xt * 16 + Xl) * BP + b) * NKB + kb] = s;
        }
        return;
    }
    // ---- q path: one block per (bp, xc)
    const int qb = bid - 288;
    const int bp = qb / 12, xc = qb - (qb / 12) * 12;
    const float* xs = x + (size_t)bp * (TT * MM) + (TT - 1) * MM;  // [c][e]
    for (int i = tid; i < MM; i += 256) {
        int c = i / SS, e = i - (i / SS) * SS;
        smem[e * 33 + c] = xs[i];
    }
    __syncthreads();
    const int c = tid & 31, grp = tid >> 5;
    const int X = xc * 8 + grp;
    const float* Vp = V + (size_t)X * MM + c;    // coalesced across c lanes
    float acc = 0.f;
#pragma unroll 8
    for (int e = 0; e < SS; ++e)
        acc = fmaf(Vp[e * CC], smem[e * 33 + c], acc);
    q[((size_t)bp * SS + X) * CC + c] = acc;     // coalesced store
}

// ---------------------------------------------------------------------------
// K4: final (grid 16 = bp): G[X] = sum_kb Gp[(X*16+bp)*48+kb] (contiguous),
// then y[bp,c] = sum_X q[bp,X,c]*G[X]. Plain store — no zeroing, no atomics.
__global__ __launch_bounds__(256) void k_final(
    const float* __restrict__ Gp, const float* __restrict__ q,
    float* __restrict__ y)
{
    const int bp = blockIdx.x, tid = threadIdx.x;
    __shared__ float Gh[SS][2];
    __shared__ float G[SS];
    __shared__ float red2[8 * CC];
    if (tid < 192) {
        const int X = tid >> 1, h = tid & 1;
        const float* p = Gp + (size_t)(X * BP + bp) * NKB + h * 24;
        float s = 0.f;
#pragma unroll
        for (int j = 0; j < 6; ++j) {
            f32x4 v4 = *(const f32x4*)(p + j * 4);
            s += v4[0] + v4[1] + v4[2] + v4[3];
        }
        Gh[X][h] = s;
    }
    __syncthreads();
    if (tid < SS) G[tid] = Gh[tid][0] + Gh[tid][1];
    __syncthreads();

    const int c = tid & 31, grp = tid >> 5;
    float acc = 0.f;
#pragma unroll
    for (int k = 0; k < 12; ++k) {
        const int X = grp * 12 + k;
        acc = fmaf(q[((size_t)bp * SS + X) * CC + c], G[X], acc);
    }
    red2[grp * CC + c] = acc;
    __syncthreads();
    if (tid < CC) {
        float s = 0.f;
#pragma unroll
        for (int g8 = 0; g8 < 8; ++g8) s += red2[g8 * CC + tid];
        y[bp * CC + tid] = s;
    }
}

// ---------------------------------------------------------------------------
extern "C" void kernel_launch(void* const* d_in, const int* in_sizes, int n_in,
                              void* d_out, int out_size, void* d_ws, size_t ws_size,
                              hipStream_t stream) {
    const float* x   = (const float*)d_in[0];
    const float* Q   = (const float*)d_in[1];
    const float* K   = (const float*)d_in[2];
    const float* V   = (const float*)d_in[3];
    const float* Aoo = (const float*)d_in[4];
    const float* w   = (const float*)d_in[5];

    char* wsb = (char*)d_ws;                       // 16B-aligned offsets
    float*          Kt  = (float*)(wsb);                    // 1,179,648 B
    float*          Gp  = (float*)(wsb + 1179648);          //   294,912 B
    float*          qb_ = (float*)(wsb + 1474560);          //   196,608 B
    unsigned short* Qb  = (unsigned short*)(wsb + 1671168); //   589,824 B
    unsigned short* wab = (unsigned short*)(wsb + 2260992); //   294,912 B
    unsigned short* xb  = (unsigned short*)(wsb + 2555904); // 1,572,864 B
    unsigned short* W2  = (unsigned short*)(wsb + 4128768); // 9,437,184 B
    float* y = (float*)d_out;                      // total ws: ~13.6 MB

    k_prep<<<dim3(288), 256, 0, stream>>>(Q, K, Aoo, w, Kt, Qb, wab);
    k_gemm1x<<<dim3(1536), 256, 0, stream>>>(Qb, wab, Kt, x, W2, xb);
    k_gemm2q<<<dim3(480), 256, 0, stream>>>(W2, xb, x, V, Gp, qb_);
    k_final<<<dim3(BP), 256, 0, stream>>>(Gp, qb_, y);
}